// Round 8
// baseline (950.140 us; speedup 1.0000x reference)
//
#include <hip/hip_runtime.h>
#include <math.h>

// SSRNet constants
#define BB   16384   // batch
#define FF   64      // fields
#define EE   16      // embedding dim
#define GG   16      // groups
#define DD   256     // d_mid_cols
#define GD   4096    // GG*DD
#define EPSV 1e-3f

typedef unsigned short u16;
typedef __attribute__((ext_vector_type(8))) short bf16x8;   // 8 bf16 = 4 VGPR
typedef __attribute__((ext_vector_type(4))) float f32x4;    // MFMA acc
#define MFMA16(a,b,c) __builtin_amdgcn_mfma_f32_16x16x32_bf16(a,b,c,0,0,0)

__device__ __forceinline__ float gelu_f(float x) {
    return 0.5f * x * (1.0f + erff(x * 0.70710678118654752f));
}
__device__ __forceinline__ u16 f2bf(float f) {
    unsigned x = __float_as_uint(f);
    return (u16)((x + 0x7fffu + ((x >> 16) & 1u)) >> 16);
}
__device__ __forceinline__ float bf2f(u16 u) {
    return __uint_as_float(((unsigned)u) << 16);
}
__device__ __forceinline__ unsigned pk2(float a, float b) {
    return (unsigned)f2bf(a) | ((unsigned)f2bf(b) << 16);
}

// ---------------------------------------------------------------------------
// Kernel 0: prepack W1,W2 -> bf16 MFMA-B-fragment layout.
// frag idx = ((gl*8 + kt)*16 + nt)*64 + lane; B[k][n]: n=lane&15,
// k = kt*32 + (lane>>4)*8 + e. gl: W1 -> g*2+l, W2 -> 32+g*2+l.
// ---------------------------------------------------------------------------
__global__ __launch_bounds__(256)
void prepack_kernel(const float* __restrict__ W1, const float* __restrict__ W2,
                    u16* __restrict__ wpack) {
    const int tid  = blockIdx.x * 256 + threadIdx.x;
    const int lane = tid & 63;
    int rest = tid >> 6;
    const int nt = rest & 15; rest >>= 4;
    const int kt = rest & 7;
    const int gl = rest >> 3;
    const float* src = (gl < 32) ? (W1 + (size_t)gl * 65536)
                                 : (W2 + (size_t)(gl - 32) * 65536);
    const int d0 = kt*32 + (lane >> 4) * 8;
    const int n  = nt*16 + (lane & 15);
    u16 o[8];
    #pragma unroll
    for (int e = 0; e < 8; ++e)
        o[e] = f2bf(src[(size_t)(d0 + e) * 256 + n]);
    uint4 pk;
    pk.x = (unsigned)o[0] | ((unsigned)o[1] << 16);
    pk.y = (unsigned)o[2] | ((unsigned)o[3] << 16);
    pk.z = (unsigned)o[4] | ((unsigned)o[5] << 16);
    pk.w = (unsigned)o[6] | ((unsigned)o[7] << 16);
    reinterpret_cast<uint4*>(wpack)[tid] = pk;
}

// ---------------------------------------------------------------------------
// Kernel 1: embed + LN(E=16) -> xflatT [1024 feat][16384 b] bf16 (TRANSPOSED)
// ---------------------------------------------------------------------------
__global__ __launch_bounds__(256)
void embed_ln_kernel(const int* __restrict__ fidx,
                     const float* __restrict__ fval,
                     const float* __restrict__ table,
                     const float* __restrict__ gamma,
                     const float* __restrict__ beta,
                     u16* __restrict__ xT) {
    __shared__ u16 lt[256 * 64];   // [feat_local 256][b_local 64] = 32KB
    const int bx = blockIdx.x;
    const int bslab = bx >> 2, fslab = bx & 3;
    const int b0 = bslab * 64;
    const int t = threadIdx.x;
    #pragma unroll
    for (int i = 0; i < 4; ++i) {
        const int c = t + i*256;           // 0..1023
        const int b = c & 63, f = c >> 6;  // f 0..15
        const int gi = (b0 + b)*FF + fslab*16 + f;
        const int row = fidx[gi];
        const float v = fval[gi];
        const float4* src = reinterpret_cast<const float4*>(table) + (size_t)row * 4;
        float4 e0 = src[0], e1 = src[1], e2 = src[2], e3 = src[3];
        float x[16] = {e0.x,e0.y,e0.z,e0.w, e1.x,e1.y,e1.z,e1.w,
                       e2.x,e2.y,e2.z,e2.w, e3.x,e3.y,e3.z,e3.w};
        float s = 0.f;
        #pragma unroll
        for (int j = 0; j < 16; ++j) { x[j] *= v; s += x[j]; }
        const float mu = s * (1.0f/16.0f);
        float q = 0.f;
        #pragma unroll
        for (int j = 0; j < 16; ++j) { float d = x[j] - mu; q += d*d; }
        const float sc = rsqrtf(q * (1.0f/16.0f) + EPSV);
        #pragma unroll
        for (int e = 0; e < 16; ++e)
            lt[(f*16 + e)*64 + b] = f2bf((x[e] - mu) * sc * gamma[e] + beta[e]);
    }
    __syncthreads();
    #pragma unroll
    for (int i = 0; i < 8; ++i) {
        const int u = t + i*256;           // uint4 id 0..2047
        const int feat = u >> 3, bq = u & 7;
        reinterpret_cast<uint4*>(xT + (size_t)(fslab*256 + feat)*BB + b0)[bq] =
            reinterpret_cast<const uint4*>(lt)[u];
    }
}

// ---------------------------------------------------------------------------
// Kernel 2: SSR block 1, MFMA. grid 4096 = (tile, g XCD-pinned), 256 thr.
// In: xflatT (coalesced row gather); out: h1T [4096][16384] bf16.
// LDS: xg 32KB + hb 32KB -> 2 blocks/CU. W (2 gl = 512KB/XCD) L2-resident.
// ---------------------------------------------------------------------------
__global__ __launch_bounds__(256, 2)
void ssr1_mfma(const u16* __restrict__ xT,      // [1024][BB]
               const int* __restrict__ idx,     // [G,256]
               const u16* __restrict__ wpack,
               const float* __restrict__ bias,  // [G,2,256]
               const float* __restrict__ gam,
               const float* __restrict__ bet,
               u16* __restrict__ h1T) {         // [4096][BB]
    __shared__ char sm[65536];
    __shared__ float musc[64][2];
    char* xg = sm;            // bf16 [64][256] swizzled: byte ^= (row&7)<<4
    char* hb = sm + 32768;

    const int bx = blockIdx.x;
    const int g  = ((bx & 7) << 1) | ((bx >> 3) & 1);
    const int b0 = (bx >> 4) * 64;
    const int t = threadIdx.x, lane = t & 63, wv = t >> 6;
    const int ln15 = lane & 15, lhi = lane >> 4;

    // gather: coalesced 128B row read from xT, LDS-transpose into xg[r][t]
    {
        const int col = idx[g*256 + t];
        const uint4* src = reinterpret_cast<const uint4*>(xT + (size_t)col*BB + b0);
        uint4 nx[8];
        #pragma unroll
        for (int j = 0; j < 8; ++j) nx[j] = src[j];
        #pragma unroll
        for (int j = 0; j < 8; ++j) {
            const unsigned uu[4] = {nx[j].x, nx[j].y, nx[j].z, nx[j].w};
            #pragma unroll
            for (int k = 0; k < 8; ++k) {
                const int r = j*8 + k;
                const int byte = (r*512 + t*2) ^ ((r & 7) << 4);
                *reinterpret_cast<u16*>(xg + byte) =
                    (k & 1) ? (u16)(uu[k >> 1] >> 16) : (u16)(uu[k >> 1] & 0xffffu);
            }
        }
    }
    __syncthreads();

    f32x4 acc[4][4];
    for (int l = 0; l < 2; ++l) {
        const char* A = l ? hb : xg;
        const bf16x8* bp = reinterpret_cast<const bf16x8*>(wpack)
                         + ((size_t)(g*2 + l) * 128 + wv*4) * 64 + lane;
        const float* bg = bias + (g*2 + l) * 256;
        #pragma unroll
        for (int nl = 0; nl < 4; ++nl) {
            const float bv = bg[(wv*4 + nl)*16 + ln15];
            #pragma unroll
            for (int rt = 0; rt < 4; ++rt) acc[rt][nl] = (f32x4){bv, bv, bv, bv};
        }
        bf16x8 bcur[4];
        #pragma unroll
        for (int nl = 0; nl < 4; ++nl) bcur[nl] = bp[nl*64];
        for (int kt = 0; kt < 8; ++kt) {
            bf16x8 bnext[4];
            if (kt < 7) {
                #pragma unroll
                for (int nl = 0; nl < 4; ++nl) bnext[nl] = bp[(kt+1)*1024 + nl*64];
            }
            bf16x8 afr[4];
            #pragma unroll
            for (int rt = 0; rt < 4; ++rt) {
                const int row = rt*16 + ln15;
                const int byte = (row*512 + kt*64 + lhi*16) ^ ((row & 7) << 4);
                afr[rt] = *reinterpret_cast<const bf16x8*>(A + byte);
            }
            #pragma unroll
            for (int rt = 0; rt < 4; ++rt)
                #pragma unroll
                for (int nl = 0; nl < 4; ++nl)
                    acc[rt][nl] = MFMA16(afr[rt], bcur[nl], acc[rt][nl]);
            #pragma unroll
            for (int nl = 0; nl < 4; ++nl) bcur[nl] = bnext[nl];
        }
        if (l == 0) {
            #pragma unroll
            for (int rt = 0; rt < 4; ++rt)
                #pragma unroll
                for (int nl = 0; nl < 4; ++nl)
                    #pragma unroll
                    for (int q = 0; q < 4; ++q) {
                        const int row = rt*16 + lhi*4 + q;
                        const int cn  = (wv*4 + nl)*16 + ln15;
                        const int byte = (row*512 + cn*2) ^ ((row & 7) << 4);
                        *reinterpret_cast<u16*>(hb + byte) = f2bf(gelu_f(acc[rt][nl][q]));
                    }
            __syncthreads();
        }
    }

    // v = gelu(acc) + x -> hb (bf16) after l=1 hb frag reads complete
    __syncthreads();
    #pragma unroll
    for (int rt = 0; rt < 4; ++rt)
        #pragma unroll
        for (int nl = 0; nl < 4; ++nl)
            #pragma unroll
            for (int q = 0; q < 4; ++q) {
                const int row = rt*16 + lhi*4 + q;
                const int cn  = (wv*4 + nl)*16 + ln15;
                const int byte = (row*512 + cn*2) ^ ((row & 7) << 4);
                const float x = bf2f(*reinterpret_cast<const u16*>(xg + byte));
                *reinterpret_cast<u16*>(hb + byte) = f2bf(gelu_f(acc[rt][nl][q]) + x);
            }
    __syncthreads();

    // LN stats: row = t>>2, quarter q4 = t&3; publish mu/sc to musc
    {
        const int row = t >> 2, q4 = t & 3;
        const int rswz = (row & 7) << 4;
        uint4 raw[8];
        #pragma unroll
        for (int i = 0; i < 8; ++i)
            raw[i] = *reinterpret_cast<const uint4*>(hb + ((row*512 + q4*128 + i*16) ^ rswz));
        float v[64];
        float s = 0.f;
        #pragma unroll
        for (int i = 0; i < 8; ++i) {
            const unsigned u[4] = {raw[i].x, raw[i].y, raw[i].z, raw[i].w};
            #pragma unroll
            for (int w = 0; w < 4; ++w) {
                const float a = bf2f((u16)(u[w] & 0xffffu));
                const float b = bf2f((u16)(u[w] >> 16));
                v[i*8 + w*2]     = a;
                v[i*8 + w*2 + 1] = b;
                s += a + b;
            }
        }
        s += __shfl_xor(s, 1); s += __shfl_xor(s, 2);
        const float mu = s * (1.0f/256.0f);
        float ss = 0.f;
        #pragma unroll
        for (int j = 0; j < 64; ++j) { const float d = v[j] - mu; ss += d*d; }
        ss += __shfl_xor(ss, 1); ss += __shfl_xor(ss, 2);
        const float sc = rsqrtf(ss * (1.0f/256.0f) + EPSV);
        if (q4 == 0) { musc[row][0] = mu; musc[row][1] = sc; }
    }
    __syncthreads();

    // transposed writer: thread t = feature cn; read hb column, write 128B row
    {
        const int cn = t;
        const float ga  = gam[g*256 + cn];
        const float bt_ = bet[g*256 + cn];
        unsigned wds[32];
        #pragma unroll
        for (int rp = 0; rp < 32; ++rp) {
            float o[2];
            #pragma unroll
            for (int h = 0; h < 2; ++h) {
                const int r = rp*2 + h;
                const u16 vv = *reinterpret_cast<const u16*>(
                    hb + ((r*512 + cn*2) ^ ((r & 7) << 4)));
                o[h] = (bf2f(vv) - musc[r][0]) * musc[r][1] * ga + bt_;
            }
            wds[rp] = pk2(o[0], o[1]);
        }
        uint4* dst = reinterpret_cast<uint4*>(h1T + (size_t)(g*256 + cn)*BB + b0);
        #pragma unroll
        for (int q = 0; q < 8; ++q)
            dst[q] = make_uint4(wds[q*4], wds[q*4+1], wds[q*4+2], wds[q*4+3]);
    }
}

// ---------------------------------------------------------------------------
// Kernel 3: SSR block 2 (4 groups per block, gset XCD-PINNED) -> bf16 partial
// ssr. grid 1024: slot = bx&7 (XCD), gset = slot>>1, tile = (bx>>3)*2+(slot&1).
// R7 post-mortem: still ~145MB spill at VGPR=128 (live ~150). This round:
// live-register diet -- (a) afr loaded in rt-PAIRS (-8), (b) LN re-unpacks
// raw[4] instead of v[32] (-16) with per-step gamma/beta loads, (c)
// launch_bounds(512,2): measured semantics arg2=blocks/CU -> cap 128 + 2
// resident blocks.
// ---------------------------------------------------------------------------
__global__ __launch_bounds__(512, 2)
void ssr2_mfma(const u16* __restrict__ h1T,   // [4096][BB]
               const int* __restrict__ idx,   // [G,256]
               const u16* __restrict__ wpack,
               const float* __restrict__ bias,
               const float* __restrict__ gam,
               const float* __restrict__ bet,
               u16* __restrict__ pssr) {      // [4][BB][256] bf16
    __shared__ char sm[65536];
    char* xg = sm;
    char* hb = sm + 32768;

    const int bx = blockIdx.x;
    const int slot = bx & 7;                  // XCD id (heuristic bx%8)
    const int gset = slot >> 1;               // 0..3, pinned per XCD pair
    const int tile = ((bx >> 3) << 1) | (slot & 1);   // 0..255
    const int b0 = tile * 64;
    const int t = threadIdx.x, lane = t & 63, wv = t >> 6;
    const int ln15 = lane & 15, lhi = lane >> 4;
    const int gd = t >> 1, grh = t & 1;       // gather: feature, r-half
    const int grow = t >> 3, goct = t & 7;    // LN/ssr mapping

    float accs[32];
    #pragma unroll
    for (int j = 0; j < 32; ++j) accs[j] = 0.f;

    uint4 nx[4];
    {   // prologue: load group gset*4
        const int col = idx[(gset*4)*256 + gd];
        const uint4* src = reinterpret_cast<const uint4*>(h1T + (size_t)col*BB + b0 + grh*32);
        #pragma unroll
        for (int j = 0; j < 4; ++j) nx[j] = src[j];
    }

    for (int gi = 0; gi < 4; ++gi) {
        const int g = gset*4 + gi;
        __syncthreads();   // xg/hb free (prev LN done)
        // LDS-transpose write of gathered rows (uses nx -> implicit vmcnt wait)
        #pragma unroll
        for (int j = 0; j < 4; ++j) {
            const unsigned uu[4] = {nx[j].x, nx[j].y, nx[j].z, nx[j].w};
            #pragma unroll
            for (int k = 0; k < 8; ++k) {
                const int r = grh*32 + j*8 + k;
                const int byte = (r*512 + gd*2) ^ ((r & 7) << 4);
                *reinterpret_cast<u16*>(xg + byte) =
                    (k & 1) ? (u16)(uu[k >> 1] >> 16) : (u16)(uu[k >> 1] & 0xffffu);
            }
        }
        if (gi < 3) {   // T14: prefetch next group's rows under the MFMA phases
            const int col = idx[(g + 1)*256 + gd];
            const uint4* src = reinterpret_cast<const uint4*>(h1T + (size_t)col*BB + b0 + grh*32);
            #pragma unroll
            for (int j = 0; j < 4; ++j) nx[j] = src[j];
        }
        __syncthreads();

        f32x4 acc[4][2];
        for (int l = 0; l < 2; ++l) {
            const char* A = l ? hb : xg;
            const bf16x8* bp = reinterpret_cast<const bf16x8*>(wpack)
                             + ((size_t)(32 + g*2 + l) * 128 + wv*2) * 64 + lane;
            const float* bg = bias + (g*2 + l) * 256;
            #pragma unroll
            for (int nl = 0; nl < 2; ++nl) {
                const float bv = bg[(wv*2 + nl)*16 + ln15];
                #pragma unroll
                for (int rt = 0; rt < 4; ++rt) acc[rt][nl] = (f32x4){bv, bv, bv, bv};
            }
            bf16x8 bcur[2];
            bcur[0] = bp[0]; bcur[1] = bp[64];
            for (int kt = 0; kt < 8; ++kt) {
                bf16x8 bnext[2];
                if (kt < 7) { bnext[0] = bp[(kt+1)*1024]; bnext[1] = bp[(kt+1)*1024 + 64]; }
                // rt-pairs: 2 A-frags live at a time (-8 VGPR vs afr[4])
                #pragma unroll
                for (int rp = 0; rp < 2; ++rp) {
                    bf16x8 afr[2];
                    #pragma unroll
                    for (int rr = 0; rr < 2; ++rr) {
                        const int rt = rp*2 + rr;
                        const int row = rt*16 + ln15;
                        const int byte = (row*512 + kt*64 + lhi*16) ^ ((row & 7) << 4);
                        afr[rr] = *reinterpret_cast<const bf16x8*>(A + byte);
                    }
                    #pragma unroll
                    for (int rr = 0; rr < 2; ++rr) {
                        const int rt = rp*2 + rr;
                        acc[rt][0] = MFMA16(afr[rr], bcur[0], acc[rt][0]);
                        acc[rt][1] = MFMA16(afr[rr], bcur[1], acc[rt][1]);
                    }
                }
                bcur[0] = bnext[0]; bcur[1] = bnext[1];
            }
            if (l == 0) {
                #pragma unroll
                for (int rt = 0; rt < 4; ++rt)
                    #pragma unroll
                    for (int nl = 0; nl < 2; ++nl)
                        #pragma unroll
                        for (int q = 0; q < 4; ++q) {
                            const int row = rt*16 + lhi*4 + q;
                            const int cn  = (wv*2 + nl)*16 + ln15;
                            const int byte = (row*512 + cn*2) ^ ((row & 7) << 4);
                            *reinterpret_cast<u16*>(hb + byte) = f2bf(gelu_f(acc[rt][nl][q]));
                        }
                __syncthreads();
            }
        }
        __syncthreads();   // l=1 hb frag reads done
        #pragma unroll
        for (int rt = 0; rt < 4; ++rt)
            #pragma unroll
            for (int nl = 0; nl < 2; ++nl)
                #pragma unroll
                for (int q = 0; q < 4; ++q) {
                    const int row = rt*16 + lhi*4 + q;
                    const int cn  = (wv*2 + nl)*16 + ln15;
                    const int byte = (row*512 + cn*2) ^ ((row & 7) << 4);
                    const float x = bf2f(*reinterpret_cast<const u16*>(xg + byte));
                    *reinterpret_cast<u16*>(hb + byte) = f2bf(gelu_f(acc[rt][nl][q]) + x);
                }
        __syncthreads();

        // LN + ssr accumulate: row = grow, cols goct*32..+32.
        // raw[4] kept packed; three unpack passes (sum / var / accumulate)
        // instead of materializing v[32] -- saves ~16 VGPR.
        {
            const int rswz = (grow & 7) << 4;
            uint4 raw[4];
            #pragma unroll
            for (int i = 0; i < 4; ++i)
                raw[i] = *reinterpret_cast<const uint4*>(hb + ((grow*512 + goct*64 + i*16) ^ rswz));
            float s = 0.f;
            #pragma unroll
            for (int i = 0; i < 4; ++i) {
                const unsigned u[4] = {raw[i].x, raw[i].y, raw[i].z, raw[i].w};
                #pragma unroll
                for (int w = 0; w < 4; ++w)
                    s += bf2f((u16)(u[w] & 0xffffu)) + bf2f((u16)(u[w] >> 16));
            }
            s += __shfl_xor(s, 1); s += __shfl_xor(s, 2); s += __shfl_xor(s, 4);
            const float mu = s * (1.0f/256.0f);
            float ss = 0.f;
            #pragma unroll
            for (int i = 0; i < 4; ++i) {
                const unsigned u[4] = {raw[i].x, raw[i].y, raw[i].z, raw[i].w};
                #pragma unroll
                for (int w = 0; w < 4; ++w) {
                    const float da = bf2f((u16)(u[w] & 0xffffu)) - mu;
                    const float db = bf2f((u16)(u[w] >> 16)) - mu;
                    ss += da*da + db*db;
                }
            }
            ss += __shfl_xor(ss, 1); ss += __shfl_xor(ss, 2); ss += __shfl_xor(ss, 4);
            const float sc = rsqrtf(ss * (1.0f/256.0f) + EPSV);
            const float4* gap = reinterpret_cast<const float4*>(gam + g*256 + goct*32);
            const float4* btp = reinterpret_cast<const float4*>(bet + g*256 + goct*32);
            #pragma unroll
            for (int i = 0; i < 4; ++i) {
                const unsigned u[4] = {raw[i].x, raw[i].y, raw[i].z, raw[i].w};
                const float4 ga0 = gap[i*2],   bt0 = btp[i*2];
                const float4 ga1 = gap[i*2+1], bt1 = btp[i*2+1];
                const float gaa[8] = {ga0.x,ga0.y,ga0.z,ga0.w, ga1.x,ga1.y,ga1.z,ga1.w};
                const float bta[8] = {bt0.x,bt0.y,bt0.z,bt0.w, bt1.x,bt1.y,bt1.z,bt1.w};
                #pragma unroll
                for (int w = 0; w < 4; ++w) {
                    const float a = bf2f((u16)(u[w] & 0xffffu));
                    const float b = bf2f((u16)(u[w] >> 16));
                    accs[i*8 + w*2]     = fmaf((a - mu)*sc*gaa[w*2]   + bta[w*2],
                                               0.0625f, accs[i*8 + w*2]);
                    accs[i*8 + w*2 + 1] = fmaf((b - mu)*sc*gaa[w*2+1] + bta[w*2+1],
                                               0.0625f, accs[i*8 + w*2 + 1]);
                }
            }
        }
        // loop-top barrier orders these hb/xg reads vs next gather writes
    }

    // store bf16 partial ssr (contiguous 64B per thread, coalesced)
    u16* dst = pssr + ((size_t)gset*BB + b0 + grow)*256 + goct*32;
    #pragma unroll
    for (int q = 0; q < 4; ++q)
        reinterpret_cast<uint4*>(dst)[q] =
            make_uint4(pk2(accs[q*8+0], accs[q*8+1]), pk2(accs[q*8+2], accs[q*8+3]),
                       pk2(accs[q*8+4], accs[q*8+5]), pk2(accs[q*8+6], accs[q*8+7]));
}

// ---------------------------------------------------------------------------
// Kernel 4: head. grid 256, 256 thr. ssr = sum of 4 bf16 partials;
// hid = relu(ssr@Wp1+bp1); out = sigmoid(hid@Wp2+bp2).
// ---------------------------------------------------------------------------
__global__ __launch_bounds__(256)
void head_kernel(const u16* __restrict__ pssr,   // [4][BB][256] bf16
                 const float* __restrict__ Wp1,  // [256,64]
                 const float* __restrict__ bp1,
                 const float* __restrict__ Wp2,
                 const float* __restrict__ bp2,
                 float* __restrict__ outp) {
    __shared__ float ssr_s[64 * 256];   // 64KB
    __shared__ float wp1_s[256 * 64];   // 64KB
    const int b0 = blockIdx.x * 64;
    const int t  = threadIdx.x;
    #pragma unroll
    for (int i = 0; i < 8; ++i) {
        const int u = t + i*256;               // uint4 id 0..2047 (8 bf16 each)
        const int row = u >> 5, c8 = u & 31;   // 32 uint4 per 256-col row
        float o[8] = {0,0,0,0,0,0,0,0};
        #pragma unroll
        for (int p = 0; p < 4; ++p) {
            const uint4 raw = reinterpret_cast<const uint4*>(
                pssr + (size_t)p*BB*256)[(size_t)(b0 + row)*32 + c8];
            const unsigned uu[4] = {raw.x, raw.y, raw.z, raw.w};
            #pragma unroll
            for (int w = 0; w < 4; ++w) {
                o[w*2]   += bf2f((u16)(uu[w] & 0xffffu));
                o[w*2+1] += bf2f((u16)(uu[w] >> 16));
            }
        }
        #pragma unroll
        for (int w = 0; w < 2; ++w)
            reinterpret_cast<float4*>(ssr_s + row*256 + c8*8)[w] =
                make_float4(o[w*4], o[w*4+1], o[w*4+2], o[w*4+3]);
    }
    #pragma unroll
    for (int i = 0; i < 16; ++i)
        reinterpret_cast<float4*>(wp1_s)[t + i*256] =
            reinterpret_cast<const float4*>(Wp1)[t + i*256];
    __syncthreads();
    const int j = t & 63, rq = t >> 6;
    const float w2j = Wp2[j], b1j = bp1[j], b2v = bp2[0];
    for (int k = 0; k < 16; ++k) {
        const int row = k*4 + rq;
        const float* sr = ssr_s + row*256;
        float s = b1j;
        #pragma unroll 8
        for (int d = 0; d < 256; ++d)
            s = fmaf(sr[d], wp1_s[d*64 + j], s);
        s = fmaxf(s, 0.f) * w2j;
        #pragma unroll
        for (int mm = 1; mm < 64; mm <<= 1) s += __shfl_xor(s, mm);
        if (j == 0) outp[b0 + row] = 1.0f / (1.0f + expf(-(s + b2v)));
    }
}

// ---------------------------------------------------------------------------
extern "C" void kernel_launch(void* const* d_in, const int* in_sizes, int n_in,
                              void* d_out, int out_size, void* d_ws, size_t ws_size,
                              hipStream_t stream) {
    const int*   fidx  = (const int*)  d_in[0];
    const float* fval  = (const float*)d_in[1];
    const float* table = (const float*)d_in[2];
    const float* ge    = (const float*)d_in[3];
    const float* be    = (const float*)d_in[4];
    const int*   idx1  = (const int*)  d_in[5];
    const float* W1    = (const float*)d_in[6];
    const float* b1    = (const float*)d_in[7];
    const float* g1    = (const float*)d_in[8];
    const float* be1   = (const float*)d_in[9];
    const int*   idx2  = (const int*)  d_in[10];
    const float* W2    = (const float*)d_in[11];
    const float* b2    = (const float*)d_in[12];
    const float* g2    = (const float*)d_in[13];
    const float* be2   = (const float*)d_in[14];
    const float* Wp1   = (const float*)d_in[15];
    const float* bp1   = (const float*)d_in[16];
    const float* Wp2   = (const float*)d_in[17];
    const float* bp2   = (const float*)d_in[18];
    float* out = (float*)d_out;

    // ws: wpack 8.4MB | xflatT bf16 [1024][BB] 32MB (overlaid by pssr bf16
    // [4][BB][256] 32MB after ssr1) | h1T bf16 [4096][BB] 128MB  (~168MB)
    const size_t wpack_elems = (size_t)64 * 8 * 16 * 64 * 8;
    const size_t need = wpack_elems*2 + (size_t)BB*1024*2 + (size_t)BB*GD*2;
    if (ws_size < need) {
        hipMemsetAsync(d_out, 0, (size_t)out_size * sizeof(float), stream);
        return;
    }
    u16* wpack = (u16*)d_ws;
    u16* xT    = wpack + wpack_elems;
    u16* pssr  = xT;                           // overlay (xT dead after ssr1)
    u16* h1T   = xT + (size_t)BB * 1024;

    prepack_kernel<<<2048, 256, 0, stream>>>(W1, W2, wpack);
    embed_ln_kernel<<<1024, 256, 0, stream>>>(fidx, fval, table, ge, be, xT);
    ssr1_mfma<<<4096, 256, 0, stream>>>(xT, idx1, wpack, b1, g1, be1, h1T);
    ssr2_mfma<<<1024, 512, 0, stream>>>(h1T, idx2, wpack, b2, g2, be2, pssr);
    head_kernel<<<256, 256, 0, stream>>>(pssr, Wp1, bp1, Wp2, bp2, out);
}

// Round 9
// 662.507 us; speedup vs baseline: 1.4342x; 1.4342x over previous
//
#include <hip/hip_runtime.h>
#include <math.h>

// SSRNet constants
#define BB   16384   // batch
#define FF   64      // fields
#define EE   16      // embedding dim
#define GG   16      // groups
#define DD   256     // d_mid_cols
#define GD   4096    // GG*DD
#define EPSV 1e-3f

typedef unsigned short u16;
typedef __attribute__((ext_vector_type(8))) short bf16x8;   // 8 bf16 = 4 VGPR
typedef __attribute__((ext_vector_type(4))) float f32x4;    // MFMA acc
#define MFMA16(a,b,c) __builtin_amdgcn_mfma_f32_16x16x32_bf16(a,b,c,0,0,0)

__device__ __forceinline__ float gelu_f(float x) {
    return 0.5f * x * (1.0f + erff(x * 0.70710678118654752f));
}
__device__ __forceinline__ u16 f2bf(float f) {
    unsigned x = __float_as_uint(f);
    return (u16)((x + 0x7fffu + ((x >> 16) & 1u)) >> 16);
}
__device__ __forceinline__ float bf2f(u16 u) {
    return __uint_as_float(((unsigned)u) << 16);
}
__device__ __forceinline__ unsigned pk2(float a, float b) {
    return (unsigned)f2bf(a) | ((unsigned)f2bf(b) << 16);
}

// ---------------------------------------------------------------------------
// Kernel 0: prepack W1,W2 -> bf16 MFMA-B-fragment layout.
// frag idx = ((gl*8 + kt)*16 + nt)*64 + lane; B[k][n]: n=lane&15,
// k = kt*32 + (lane>>4)*8 + e. gl: W1 -> g*2+l, W2 -> 32+g*2+l.
// ---------------------------------------------------------------------------
__global__ __launch_bounds__(256)
void prepack_kernel(const float* __restrict__ W1, const float* __restrict__ W2,
                    u16* __restrict__ wpack) {
    const int tid  = blockIdx.x * 256 + threadIdx.x;
    const int lane = tid & 63;
    int rest = tid >> 6;
    const int nt = rest & 15; rest >>= 4;
    const int kt = rest & 7;
    const int gl = rest >> 3;
    const float* src = (gl < 32) ? (W1 + (size_t)gl * 65536)
                                 : (W2 + (size_t)(gl - 32) * 65536);
    const int d0 = kt*32 + (lane >> 4) * 8;
    const int n  = nt*16 + (lane & 15);
    u16 o[8];
    #pragma unroll
    for (int e = 0; e < 8; ++e)
        o[e] = f2bf(src[(size_t)(d0 + e) * 256 + n]);
    uint4 pk;
    pk.x = (unsigned)o[0] | ((unsigned)o[1] << 16);
    pk.y = (unsigned)o[2] | ((unsigned)o[3] << 16);
    pk.z = (unsigned)o[4] | ((unsigned)o[5] << 16);
    pk.w = (unsigned)o[6] | ((unsigned)o[7] << 16);
    reinterpret_cast<uint4*>(wpack)[tid] = pk;
}

// ---------------------------------------------------------------------------
// Kernel 1: embed + LN(E=16) -> xflatT [1024 feat][16384 b] bf16 (TRANSPOSED)
// ---------------------------------------------------------------------------
__global__ __launch_bounds__(256)
void embed_ln_kernel(const int* __restrict__ fidx,
                     const float* __restrict__ fval,
                     const float* __restrict__ table,
                     const float* __restrict__ gamma,
                     const float* __restrict__ beta,
                     u16* __restrict__ xT) {
    __shared__ u16 lt[256 * 64];   // [feat_local 256][b_local 64] = 32KB
    const int bx = blockIdx.x;
    const int bslab = bx >> 2, fslab = bx & 3;
    const int b0 = bslab * 64;
    const int t = threadIdx.x;
    #pragma unroll
    for (int i = 0; i < 4; ++i) {
        const int c = t + i*256;           // 0..1023
        const int b = c & 63, f = c >> 6;  // f 0..15
        const int gi = (b0 + b)*FF + fslab*16 + f;
        const int row = fidx[gi];
        const float v = fval[gi];
        const float4* src = reinterpret_cast<const float4*>(table) + (size_t)row * 4;
        float4 e0 = src[0], e1 = src[1], e2 = src[2], e3 = src[3];
        float x[16] = {e0.x,e0.y,e0.z,e0.w, e1.x,e1.y,e1.z,e1.w,
                       e2.x,e2.y,e2.z,e2.w, e3.x,e3.y,e3.z,e3.w};
        float s = 0.f;
        #pragma unroll
        for (int j = 0; j < 16; ++j) { x[j] *= v; s += x[j]; }
        const float mu = s * (1.0f/16.0f);
        float q = 0.f;
        #pragma unroll
        for (int j = 0; j < 16; ++j) { float d = x[j] - mu; q += d*d; }
        const float sc = rsqrtf(q * (1.0f/16.0f) + EPSV);
        #pragma unroll
        for (int e = 0; e < 16; ++e)
            lt[(f*16 + e)*64 + b] = f2bf((x[e] - mu) * sc * gamma[e] + beta[e]);
    }
    __syncthreads();
    #pragma unroll
    for (int i = 0; i < 8; ++i) {
        const int u = t + i*256;           // uint4 id 0..2047
        const int feat = u >> 3, bq = u & 7;
        reinterpret_cast<uint4*>(xT + (size_t)(fslab*256 + feat)*BB + b0)[bq] =
            reinterpret_cast<const uint4*>(lt)[u];
    }
}

// ---------------------------------------------------------------------------
// Kernel 2: SSR block 1, MFMA. grid 4096 = (tile, g XCD-pinned), 256 thr.
// In: xflatT (coalesced row gather); out: h1T [4096][16384] bf16.
// LDS: xg 32KB + hb 32KB -> 2 blocks/CU. W (2 gl = 512KB/XCD) L2-resident.
// ---------------------------------------------------------------------------
__global__ __launch_bounds__(256, 2)
void ssr1_mfma(const u16* __restrict__ xT,      // [1024][BB]
               const int* __restrict__ idx,     // [G,256]
               const u16* __restrict__ wpack,
               const float* __restrict__ bias,  // [G,2,256]
               const float* __restrict__ gam,
               const float* __restrict__ bet,
               u16* __restrict__ h1T) {         // [4096][BB]
    __shared__ char sm[65536];
    __shared__ float musc[64][2];
    char* xg = sm;            // bf16 [64][256] swizzled: byte ^= (row&7)<<4
    char* hb = sm + 32768;

    const int bx = blockIdx.x;
    const int g  = ((bx & 7) << 1) | ((bx >> 3) & 1);
    const int b0 = (bx >> 4) * 64;
    const int t = threadIdx.x, lane = t & 63, wv = t >> 6;
    const int ln15 = lane & 15, lhi = lane >> 4;

    // gather: coalesced 128B row read from xT, LDS-transpose into xg[r][t]
    {
        const int col = idx[g*256 + t];
        const uint4* src = reinterpret_cast<const uint4*>(xT + (size_t)col*BB + b0);
        uint4 nx[8];
        #pragma unroll
        for (int j = 0; j < 8; ++j) nx[j] = src[j];
        #pragma unroll
        for (int j = 0; j < 8; ++j) {
            const unsigned uu[4] = {nx[j].x, nx[j].y, nx[j].z, nx[j].w};
            #pragma unroll
            for (int k = 0; k < 8; ++k) {
                const int r = j*8 + k;
                const int byte = (r*512 + t*2) ^ ((r & 7) << 4);
                *reinterpret_cast<u16*>(xg + byte) =
                    (k & 1) ? (u16)(uu[k >> 1] >> 16) : (u16)(uu[k >> 1] & 0xffffu);
            }
        }
    }
    __syncthreads();

    f32x4 acc[4][4];
    for (int l = 0; l < 2; ++l) {
        const char* A = l ? hb : xg;
        const bf16x8* bp = reinterpret_cast<const bf16x8*>(wpack)
                         + ((size_t)(g*2 + l) * 128 + wv*4) * 64 + lane;
        const float* bg = bias + (g*2 + l) * 256;
        #pragma unroll
        for (int nl = 0; nl < 4; ++nl) {
            const float bv = bg[(wv*4 + nl)*16 + ln15];
            #pragma unroll
            for (int rt = 0; rt < 4; ++rt) acc[rt][nl] = (f32x4){bv, bv, bv, bv};
        }
        bf16x8 bcur[4];
        #pragma unroll
        for (int nl = 0; nl < 4; ++nl) bcur[nl] = bp[nl*64];
        for (int kt = 0; kt < 8; ++kt) {
            bf16x8 bnext[4];
            if (kt < 7) {
                #pragma unroll
                for (int nl = 0; nl < 4; ++nl) bnext[nl] = bp[(kt+1)*1024 + nl*64];
            }
            bf16x8 afr[4];
            #pragma unroll
            for (int rt = 0; rt < 4; ++rt) {
                const int row = rt*16 + ln15;
                const int byte = (row*512 + kt*64 + lhi*16) ^ ((row & 7) << 4);
                afr[rt] = *reinterpret_cast<const bf16x8*>(A + byte);
            }
            #pragma unroll
            for (int rt = 0; rt < 4; ++rt)
                #pragma unroll
                for (int nl = 0; nl < 4; ++nl)
                    acc[rt][nl] = MFMA16(afr[rt], bcur[nl], acc[rt][nl]);
            #pragma unroll
            for (int nl = 0; nl < 4; ++nl) bcur[nl] = bnext[nl];
        }
        if (l == 0) {
            #pragma unroll
            for (int rt = 0; rt < 4; ++rt)
                #pragma unroll
                for (int nl = 0; nl < 4; ++nl)
                    #pragma unroll
                    for (int q = 0; q < 4; ++q) {
                        const int row = rt*16 + lhi*4 + q;
                        const int cn  = (wv*4 + nl)*16 + ln15;
                        const int byte = (row*512 + cn*2) ^ ((row & 7) << 4);
                        *reinterpret_cast<u16*>(hb + byte) = f2bf(gelu_f(acc[rt][nl][q]));
                    }
            __syncthreads();
        }
    }

    // v = gelu(acc) + x -> hb (bf16) after l=1 hb frag reads complete
    __syncthreads();
    #pragma unroll
    for (int rt = 0; rt < 4; ++rt)
        #pragma unroll
        for (int nl = 0; nl < 4; ++nl)
            #pragma unroll
            for (int q = 0; q < 4; ++q) {
                const int row = rt*16 + lhi*4 + q;
                const int cn  = (wv*4 + nl)*16 + ln15;
                const int byte = (row*512 + cn*2) ^ ((row & 7) << 4);
                const float x = bf2f(*reinterpret_cast<const u16*>(xg + byte));
                *reinterpret_cast<u16*>(hb + byte) = f2bf(gelu_f(acc[rt][nl][q]) + x);
            }
    __syncthreads();

    // LN stats: row = t>>2, quarter q4 = t&3; publish mu/sc to musc
    {
        const int row = t >> 2, q4 = t & 3;
        const int rswz = (row & 7) << 4;
        uint4 raw[8];
        #pragma unroll
        for (int i = 0; i < 8; ++i)
            raw[i] = *reinterpret_cast<const uint4*>(hb + ((row*512 + q4*128 + i*16) ^ rswz));
        float v[64];
        float s = 0.f;
        #pragma unroll
        for (int i = 0; i < 8; ++i) {
            const unsigned u[4] = {raw[i].x, raw[i].y, raw[i].z, raw[i].w};
            #pragma unroll
            for (int w = 0; w < 4; ++w) {
                const float a = bf2f((u16)(u[w] & 0xffffu));
                const float b = bf2f((u16)(u[w] >> 16));
                v[i*8 + w*2]     = a;
                v[i*8 + w*2 + 1] = b;
                s += a + b;
            }
        }
        s += __shfl_xor(s, 1); s += __shfl_xor(s, 2);
        const float mu = s * (1.0f/256.0f);
        float ss = 0.f;
        #pragma unroll
        for (int j = 0; j < 64; ++j) { const float d = v[j] - mu; ss += d*d; }
        ss += __shfl_xor(ss, 1); ss += __shfl_xor(ss, 2);
        const float sc = rsqrtf(ss * (1.0f/256.0f) + EPSV);
        if (q4 == 0) { musc[row][0] = mu; musc[row][1] = sc; }
    }
    __syncthreads();

    // transposed writer: thread t = feature cn; read hb column, write 128B row
    {
        const int cn = t;
        const float ga  = gam[g*256 + cn];
        const float bt_ = bet[g*256 + cn];
        unsigned wds[32];
        #pragma unroll
        for (int rp = 0; rp < 32; ++rp) {
            float o[2];
            #pragma unroll
            for (int h = 0; h < 2; ++h) {
                const int r = rp*2 + h;
                const u16 vv = *reinterpret_cast<const u16*>(
                    hb + ((r*512 + cn*2) ^ ((r & 7) << 4)));
                o[h] = (bf2f(vv) - musc[r][0]) * musc[r][1] * ga + bt_;
            }
            wds[rp] = pk2(o[0], o[1]);
        }
        uint4* dst = reinterpret_cast<uint4*>(h1T + (size_t)(g*256 + cn)*BB + b0);
        #pragma unroll
        for (int q = 0; q < 8; ++q)
            dst[q] = make_uint4(wds[q*4], wds[q*4+1], wds[q*4+2], wds[q*4+3]);
    }
}

// ---------------------------------------------------------------------------
// Kernel 3: SSR block 2, BM=32 rows/block (R8 post-mortem: BM=64's persistent
// accs[32]+acc[32] put phase-peak ~150 VGPR > 128 -> unavoidable spill, 3
// rounds of trimming failed). BM=32 halves all per-thread state (~90 live,
// no spill, natural allocation). grid 2048: slot=bx&7 (XCD), gset=slot>>1,
// tile = (slot&1)*256 + (bx>>3) -> contiguous batch range per XCD parity.
// LDS 32KB -> 2-3 blocks/CU.
// ---------------------------------------------------------------------------
__global__ __launch_bounds__(512, 1)
void ssr2_mfma(const u16* __restrict__ h1T,   // [4096][BB]
               const int* __restrict__ idx,   // [G,256]
               const u16* __restrict__ wpack,
               const float* __restrict__ bias,
               const float* __restrict__ gam,
               const float* __restrict__ bet,
               u16* __restrict__ pssr) {      // [4][BB][256] bf16
    __shared__ char sm[32768];
    char* xg = sm;            // bf16 [32][256] swizzled
    char* hb = sm + 16384;

    const int bx = blockIdx.x;
    const int slot = bx & 7;                  // XCD id (heuristic bx%8)
    const int gset = slot >> 1;               // 0..3, pinned per XCD pair
    const int tile = ((slot & 1) << 8) | (bx >> 3);   // 0..511
    const int b0 = tile * 32;
    const int t = threadIdx.x, lane = t & 63, wv = t >> 6;
    const int ln15 = lane & 15, lhi = lane >> 4;
    const int gd = t >> 1, grh = t & 1;       // gather: feature, batch-half
    const int grow = t >> 4, gc16 = t & 15;   // LN/ssr: row, col-16-block

    float accs[16];
    #pragma unroll
    for (int j = 0; j < 16; ++j) accs[j] = 0.f;

    uint4 nx[2];
    {   // prologue: load group gset*4
        const int col = idx[(gset*4)*256 + gd];
        const uint4* src = reinterpret_cast<const uint4*>(h1T + (size_t)col*BB + b0 + grh*16);
        nx[0] = src[0]; nx[1] = src[1];
    }

    for (int gi = 0; gi < 4; ++gi) {
        const int g = gset*4 + gi;
        __syncthreads();   // xg/hb free (prev LN done)
        // LDS-transpose write of gathered rows (uses nx -> implicit vmcnt wait)
        #pragma unroll
        for (int j = 0; j < 2; ++j) {
            const unsigned uu[4] = {nx[j].x, nx[j].y, nx[j].z, nx[j].w};
            #pragma unroll
            for (int k = 0; k < 8; ++k) {
                const int r = grh*16 + j*8 + k;
                const int byte = (r*512 + gd*2) ^ ((r & 7) << 4);
                *reinterpret_cast<u16*>(xg + byte) =
                    (k & 1) ? (u16)(uu[k >> 1] >> 16) : (u16)(uu[k >> 1] & 0xffffu);
            }
        }
        if (gi < 3) {   // T14: prefetch next group's rows under the MFMA phases
            const int col = idx[(g + 1)*256 + gd];
            const uint4* src = reinterpret_cast<const uint4*>(h1T + (size_t)col*BB + b0 + grh*16);
            nx[0] = src[0]; nx[1] = src[1];
        }
        __syncthreads();

        f32x4 acc[2][2];
        for (int l = 0; l < 2; ++l) {
            const char* A = l ? hb : xg;
            const bf16x8* bp = reinterpret_cast<const bf16x8*>(wpack)
                             + ((size_t)(32 + g*2 + l) * 128 + wv*2) * 64 + lane;
            const float* bg = bias + (g*2 + l) * 256;
            #pragma unroll
            for (int nl = 0; nl < 2; ++nl) {
                const float bv = bg[(wv*2 + nl)*16 + ln15];
                #pragma unroll
                for (int rt = 0; rt < 2; ++rt) acc[rt][nl] = (f32x4){bv, bv, bv, bv};
            }
            bf16x8 bcur[2];
            bcur[0] = bp[0]; bcur[1] = bp[64];
            for (int kt = 0; kt < 8; ++kt) {
                bf16x8 bnext[2];
                if (kt < 7) { bnext[0] = bp[(kt+1)*1024]; bnext[1] = bp[(kt+1)*1024 + 64]; }
                bf16x8 afr[2];
                #pragma unroll
                for (int rt = 0; rt < 2; ++rt) {
                    const int row = rt*16 + ln15;
                    const int byte = (row*512 + kt*64 + lhi*16) ^ ((row & 7) << 4);
                    afr[rt] = *reinterpret_cast<const bf16x8*>(A + byte);
                }
                #pragma unroll
                for (int rt = 0; rt < 2; ++rt) {
                    acc[rt][0] = MFMA16(afr[rt], bcur[0], acc[rt][0]);
                    acc[rt][1] = MFMA16(afr[rt], bcur[1], acc[rt][1]);
                }
                bcur[0] = bnext[0]; bcur[1] = bnext[1];
            }
            if (l == 0) {
                #pragma unroll
                for (int rt = 0; rt < 2; ++rt)
                    #pragma unroll
                    for (int nl = 0; nl < 2; ++nl)
                        #pragma unroll
                        for (int q = 0; q < 4; ++q) {
                            const int row = rt*16 + lhi*4 + q;
                            const int cn  = (wv*2 + nl)*16 + ln15;
                            const int byte = (row*512 + cn*2) ^ ((row & 7) << 4);
                            *reinterpret_cast<u16*>(hb + byte) = f2bf(gelu_f(acc[rt][nl][q]));
                        }
                __syncthreads();
            }
        }
        __syncthreads();   // l=1 hb frag reads done
        #pragma unroll
        for (int rt = 0; rt < 2; ++rt)
            #pragma unroll
            for (int nl = 0; nl < 2; ++nl)
                #pragma unroll
                for (int q = 0; q < 4; ++q) {
                    const int row = rt*16 + lhi*4 + q;
                    const int cn  = (wv*2 + nl)*16 + ln15;
                    const int byte = (row*512 + cn*2) ^ ((row & 7) << 4);
                    const float x = bf2f(*reinterpret_cast<const u16*>(xg + byte));
                    *reinterpret_cast<u16*>(hb + byte) = f2bf(gelu_f(acc[rt][nl][q]) + x);
                }
        __syncthreads();

        // LN + ssr accumulate: row = grow (0..31), cols gc16*16..+16.
        // 16 threads/row -> shfl_xor over 1,2,4,8 (lane groups of 16).
        {
            const int rswz = (grow & 7) << 4;
            uint4 raw[2];
            #pragma unroll
            for (int i = 0; i < 2; ++i)
                raw[i] = *reinterpret_cast<const uint4*>(hb + ((grow*512 + gc16*32 + i*16) ^ rswz));
            float s = 0.f;
            #pragma unroll
            for (int i = 0; i < 2; ++i) {
                const unsigned u[4] = {raw[i].x, raw[i].y, raw[i].z, raw[i].w};
                #pragma unroll
                for (int w = 0; w < 4; ++w)
                    s += bf2f((u16)(u[w] & 0xffffu)) + bf2f((u16)(u[w] >> 16));
            }
            s += __shfl_xor(s, 1); s += __shfl_xor(s, 2);
            s += __shfl_xor(s, 4); s += __shfl_xor(s, 8);
            const float mu = s * (1.0f/256.0f);
            float ss = 0.f;
            #pragma unroll
            for (int i = 0; i < 2; ++i) {
                const unsigned u[4] = {raw[i].x, raw[i].y, raw[i].z, raw[i].w};
                #pragma unroll
                for (int w = 0; w < 4; ++w) {
                    const float da = bf2f((u16)(u[w] & 0xffffu)) - mu;
                    const float db = bf2f((u16)(u[w] >> 16)) - mu;
                    ss += da*da + db*db;
                }
            }
            ss += __shfl_xor(ss, 1); ss += __shfl_xor(ss, 2);
            ss += __shfl_xor(ss, 4); ss += __shfl_xor(ss, 8);
            const float sc = rsqrtf(ss * (1.0f/256.0f) + EPSV);
            const float4* gap = reinterpret_cast<const float4*>(gam + g*256 + gc16*16);
            const float4* btp = reinterpret_cast<const float4*>(bet + g*256 + gc16*16);
            #pragma unroll
            for (int i = 0; i < 2; ++i) {
                const unsigned u[4] = {raw[i].x, raw[i].y, raw[i].z, raw[i].w};
                const float4 ga0 = gap[i*2],   bt0 = btp[i*2];
                const float4 ga1 = gap[i*2+1], bt1 = btp[i*2+1];
                const float gaa[8] = {ga0.x,ga0.y,ga0.z,ga0.w, ga1.x,ga1.y,ga1.z,ga1.w};
                const float bta[8] = {bt0.x,bt0.y,bt0.z,bt0.w, bt1.x,bt1.y,bt1.z,bt1.w};
                #pragma unroll
                for (int w = 0; w < 4; ++w) {
                    const float a = bf2f((u16)(u[w] & 0xffffu));
                    const float b = bf2f((u16)(u[w] >> 16));
                    accs[i*8 + w*2]     = fmaf((a - mu)*sc*gaa[w*2]   + bta[w*2],
                                               0.0625f, accs[i*8 + w*2]);
                    accs[i*8 + w*2 + 1] = fmaf((b - mu)*sc*gaa[w*2+1] + bta[w*2+1],
                                               0.0625f, accs[i*8 + w*2 + 1]);
                }
            }
        }
        // loop-top barrier orders these hb/xg reads vs next gather writes
    }

    // store bf16 partial ssr (contiguous 32B per thread, coalesced)
    u16* dst = pssr + ((size_t)gset*BB + b0 + grow)*256 + gc16*16;
    #pragma unroll
    for (int q = 0; q < 2; ++q)
        reinterpret_cast<uint4*>(dst)[q] =
            make_uint4(pk2(accs[q*8+0], accs[q*8+1]), pk2(accs[q*8+2], accs[q*8+3]),
                       pk2(accs[q*8+4], accs[q*8+5]), pk2(accs[q*8+6], accs[q*8+7]));
}

// ---------------------------------------------------------------------------
// Kernel 4: head. grid 256, 256 thr. ssr = sum of 4 bf16 partials;
// hid = relu(ssr@Wp1+bp1); out = sigmoid(hid@Wp2+bp2).
// ---------------------------------------------------------------------------
__global__ __launch_bounds__(256)
void head_kernel(const u16* __restrict__ pssr,   // [4][BB][256] bf16
                 const float* __restrict__ Wp1,  // [256,64]
                 const float* __restrict__ bp1,
                 const float* __restrict__ Wp2,
                 const float* __restrict__ bp2,
                 float* __restrict__ outp) {
    __shared__ float ssr_s[64 * 256];   // 64KB
    __shared__ float wp1_s[256 * 64];   // 64KB
    const int b0 = blockIdx.x * 64;
    const int t  = threadIdx.x;
    #pragma unroll
    for (int i = 0; i < 8; ++i) {
        const int u = t + i*256;               // uint4 id 0..2047 (8 bf16 each)
        const int row = u >> 5, c8 = u & 31;   // 32 uint4 per 256-col row
        float o[8] = {0,0,0,0,0,0,0,0};
        #pragma unroll
        for (int p = 0; p < 4; ++p) {
            const uint4 raw = reinterpret_cast<const uint4*>(
                pssr + (size_t)p*BB*256)[(size_t)(b0 + row)*32 + c8];
            const unsigned uu[4] = {raw.x, raw.y, raw.z, raw.w};
            #pragma unroll
            for (int w = 0; w < 4; ++w) {
                o[w*2]   += bf2f((u16)(uu[w] & 0xffffu));
                o[w*2+1] += bf2f((u16)(uu[w] >> 16));
            }
        }
        #pragma unroll
        for (int w = 0; w < 2; ++w)
            reinterpret_cast<float4*>(ssr_s + row*256 + c8*8)[w] =
                make_float4(o[w*4], o[w*4+1], o[w*4+2], o[w*4+3]);
    }
    #pragma unroll
    for (int i = 0; i < 16; ++i)
        reinterpret_cast<float4*>(wp1_s)[t + i*256] =
            reinterpret_cast<const float4*>(Wp1)[t + i*256];
    __syncthreads();
    const int j = t & 63, rq = t >> 6;
    const float w2j = Wp2[j], b1j = bp1[j], b2v = bp2[0];
    for (int k = 0; k < 16; ++k) {
        const int row = k*4 + rq;
        const float* sr = ssr_s + row*256;
        float s = b1j;
        #pragma unroll 8
        for (int d = 0; d < 256; ++d)
            s = fmaf(sr[d], wp1_s[d*64 + j], s);
        s = fmaxf(s, 0.f) * w2j;
        #pragma unroll
        for (int mm = 1; mm < 64; mm <<= 1) s += __shfl_xor(s, mm);
        if (j == 0) outp[b0 + row] = 1.0f / (1.0f + expf(-(s + b2v)));
    }
}

// ---------------------------------------------------------------------------
extern "C" void kernel_launch(void* const* d_in, const int* in_sizes, int n_in,
                              void* d_out, int out_size, void* d_ws, size_t ws_size,
                              hipStream_t stream) {
    const int*   fidx  = (const int*)  d_in[0];
    const float* fval  = (const float*)d_in[1];
    const float* table = (const float*)d_in[2];
    const float* ge    = (const float*)d_in[3];
    const float* be    = (const float*)d_in[4];
    const int*   idx1  = (const int*)  d_in[5];
    const float* W1    = (const float*)d_in[6];
    const float* b1    = (const float*)d_in[7];
    const float* g1    = (const float*)d_in[8];
    const float* be1   = (const float*)d_in[9];
    const int*   idx2  = (const int*)  d_in[10];
    const float* W2    = (const float*)d_in[11];
    const float* b2    = (const float*)d_in[12];
    const float* g2    = (const float*)d_in[13];
    const float* be2   = (const float*)d_in[14];
    const float* Wp1   = (const float*)d_in[15];
    const float* bp1   = (const float*)d_in[16];
    const float* Wp2   = (const float*)d_in[17];
    const float* bp2   = (const float*)d_in[18];
    float* out = (float*)d_out;

    // ws: wpack 8.4MB | xflatT bf16 [1024][BB] 32MB (overlaid by pssr bf16
    // [4][BB][256] 32MB after ssr1) | h1T bf16 [4096][BB] 128MB  (~168MB)
    const size_t wpack_elems = (size_t)64 * 8 * 16 * 64 * 8;
    const size_t need = wpack_elems*2 + (size_t)BB*1024*2 + (size_t)BB*GD*2;
    if (ws_size < need) {
        hipMemsetAsync(d_out, 0, (size_t)out_size * sizeof(float), stream);
        return;
    }
    u16* wpack = (u16*)d_ws;
    u16* xT    = wpack + wpack_elems;
    u16* pssr  = xT;                           // overlay (xT dead after ssr1)
    u16* h1T   = xT + (size_t)BB * 1024;

    prepack_kernel<<<2048, 256, 0, stream>>>(W1, W2, wpack);
    embed_ln_kernel<<<1024, 256, 0, stream>>>(fidx, fval, table, ge, be, xT);
    ssr1_mfma<<<4096, 256, 0, stream>>>(xT, idx1, wpack, b1, g1, be1, h1T);
    ssr2_mfma<<<2048, 512, 0, stream>>>(h1T, idx2, wpack, b2, g2, be2, pssr);
    head_kernel<<<256, 256, 0, stream>>>(pssr, Wp1, bp1, Wp2, bp2, out);
}

// Round 10
// 635.007 us; speedup vs baseline: 1.4963x; 1.0433x over previous
//
#include <hip/hip_runtime.h>
#include <math.h>

// SSRNet constants
#define BB   16384   // batch
#define FF   64      // fields
#define EE   16      // embedding dim
#define GG   16      // groups
#define DD   256     // d_mid_cols
#define GD   4096    // GG*DD
#define EPSV 1e-3f

typedef unsigned short u16;
typedef __attribute__((ext_vector_type(8))) short bf16x8;   // 8 bf16 = 4 VGPR
typedef __attribute__((ext_vector_type(4))) float f32x4;    // MFMA acc
#define MFMA16(a,b,c) __builtin_amdgcn_mfma_f32_16x16x32_bf16(a,b,c,0,0,0)

__device__ __forceinline__ float gelu_f(float x) {
    return 0.5f * x * (1.0f + erff(x * 0.70710678118654752f));
}
__device__ __forceinline__ u16 f2bf(float f) {
    unsigned x = __float_as_uint(f);
    return (u16)((x + 0x7fffu + ((x >> 16) & 1u)) >> 16);
}
__device__ __forceinline__ float bf2f(u16 u) {
    return __uint_as_float(((unsigned)u) << 16);
}
__device__ __forceinline__ unsigned pk2(float a, float b) {
    return (unsigned)f2bf(a) | ((unsigned)f2bf(b) << 16);
}

// ---------------------------------------------------------------------------
// Kernel 0: prepack W1,W2 -> bf16 MFMA-B-fragment layout.
// frag idx = ((gl*8 + kt)*16 + nt)*64 + lane; B[k][n]: n=lane&15,
// k = kt*32 + (lane>>4)*8 + e. gl: W1 -> g*2+l, W2 -> 32+g*2+l.
// ---------------------------------------------------------------------------
__global__ __launch_bounds__(256)
void prepack_kernel(const float* __restrict__ W1, const float* __restrict__ W2,
                    u16* __restrict__ wpack) {
    const int tid  = blockIdx.x * 256 + threadIdx.x;
    const int lane = tid & 63;
    int rest = tid >> 6;
    const int nt = rest & 15; rest >>= 4;
    const int kt = rest & 7;
    const int gl = rest >> 3;
    const float* src = (gl < 32) ? (W1 + (size_t)gl * 65536)
                                 : (W2 + (size_t)(gl - 32) * 65536);
    const int d0 = kt*32 + (lane >> 4) * 8;
    const int n  = nt*16 + (lane & 15);
    u16 o[8];
    #pragma unroll
    for (int e = 0; e < 8; ++e)
        o[e] = f2bf(src[(size_t)(d0 + e) * 256 + n]);
    uint4 pk;
    pk.x = (unsigned)o[0] | ((unsigned)o[1] << 16);
    pk.y = (unsigned)o[2] | ((unsigned)o[3] << 16);
    pk.z = (unsigned)o[4] | ((unsigned)o[5] << 16);
    pk.w = (unsigned)o[6] | ((unsigned)o[7] << 16);
    reinterpret_cast<uint4*>(wpack)[tid] = pk;
}

// ---------------------------------------------------------------------------
// Kernel 1: embed + LN(E=16) -> xflatT [1024 feat][16384 b] bf16 (TRANSPOSED)
// ---------------------------------------------------------------------------
__global__ __launch_bounds__(256)
void embed_ln_kernel(const int* __restrict__ fidx,
                     const float* __restrict__ fval,
                     const float* __restrict__ table,
                     const float* __restrict__ gamma,
                     const float* __restrict__ beta,
                     u16* __restrict__ xT) {
    __shared__ u16 lt[256 * 64];   // [feat_local 256][b_local 64] = 32KB
    const int bx = blockIdx.x;
    const int bslab = bx >> 2, fslab = bx & 3;
    const int b0 = bslab * 64;
    const int t = threadIdx.x;
    #pragma unroll
    for (int i = 0; i < 4; ++i) {
        const int c = t + i*256;           // 0..1023
        const int b = c & 63, f = c >> 6;  // f 0..15
        const int gi = (b0 + b)*FF + fslab*16 + f;
        const int row = fidx[gi];
        const float v = fval[gi];
        const float4* src = reinterpret_cast<const float4*>(table) + (size_t)row * 4;
        float4 e0 = src[0], e1 = src[1], e2 = src[2], e3 = src[3];
        float x[16] = {e0.x,e0.y,e0.z,e0.w, e1.x,e1.y,e1.z,e1.w,
                       e2.x,e2.y,e2.z,e2.w, e3.x,e3.y,e3.z,e3.w};
        float s = 0.f;
        #pragma unroll
        for (int j = 0; j < 16; ++j) { x[j] *= v; s += x[j]; }
        const float mu = s * (1.0f/16.0f);
        float q = 0.f;
        #pragma unroll
        for (int j = 0; j < 16; ++j) { float d = x[j] - mu; q += d*d; }
        const float sc = rsqrtf(q * (1.0f/16.0f) + EPSV);
        #pragma unroll
        for (int e = 0; e < 16; ++e)
            lt[(f*16 + e)*64 + b] = f2bf((x[e] - mu) * sc * gamma[e] + beta[e]);
    }
    __syncthreads();
    #pragma unroll
    for (int i = 0; i < 8; ++i) {
        const int u = t + i*256;           // uint4 id 0..2047
        const int feat = u >> 3, bq = u & 7;
        reinterpret_cast<uint4*>(xT + (size_t)(fslab*256 + feat)*BB + b0)[bq] =
            reinterpret_cast<const uint4*>(lt)[u];
    }
}

// ---------------------------------------------------------------------------
// Kernel 2: SSR block 1, MFMA, BM=32 (R9 lesson: small tile -> no spill, high
// occupancy). grid 8192 = (tile 512, g XCD-pinned), 256 thr (4 waves).
// LDS: xg 16KB + hb 16KB + musc -> 4 blocks/CU (132KB). VGPR ~95, cap 128.
// Wave wv owns cols wv*64..+64 (acc[2][4]); rows all 32.
// ---------------------------------------------------------------------------
__global__ __launch_bounds__(256, 4)
void ssr1_mfma(const u16* __restrict__ xT,      // [1024][BB]
               const int* __restrict__ idx,     // [G,256]
               const u16* __restrict__ wpack,
               const float* __restrict__ bias,  // [G,2,256]
               const float* __restrict__ gam,
               const float* __restrict__ bet,
               u16* __restrict__ h1T) {         // [4096][BB]
    __shared__ char sm[32768];
    __shared__ float musc[32][2];
    char* xg = sm;            // bf16 [32][256] swizzled: byte ^= (row&7)<<4
    char* hb = sm + 16384;

    const int bx = blockIdx.x;
    const int g  = ((bx & 7) << 1) | ((bx >> 3) & 1);
    const int b0 = (bx >> 4) * 32;
    const int t = threadIdx.x, lane = t & 63, wv = t >> 6;
    const int ln15 = lane & 15, lhi = lane >> 4;

    // gather: thread t = feature col; 64B contiguous read; LDS-transpose
    {
        const int col = idx[g*256 + t];
        const uint4* src = reinterpret_cast<const uint4*>(xT + (size_t)col*BB + b0);
        uint4 nx[4];
        #pragma unroll
        for (int j = 0; j < 4; ++j) nx[j] = src[j];
        #pragma unroll
        for (int j = 0; j < 4; ++j) {
            const unsigned uu[4] = {nx[j].x, nx[j].y, nx[j].z, nx[j].w};
            #pragma unroll
            for (int k = 0; k < 8; ++k) {
                const int r = j*8 + k;
                const int byte = (r*512 + t*2) ^ ((r & 7) << 4);
                *reinterpret_cast<u16*>(xg + byte) =
                    (k & 1) ? (u16)(uu[k >> 1] >> 16) : (u16)(uu[k >> 1] & 0xffffu);
            }
        }
    }
    __syncthreads();

    f32x4 acc[2][4];
    for (int l = 0; l < 2; ++l) {
        const char* A = l ? hb : xg;
        const bf16x8* bp = reinterpret_cast<const bf16x8*>(wpack)
                         + ((size_t)(g*2 + l) * 128 + wv*4) * 64 + lane;
        const float* bg = bias + (g*2 + l) * 256;
        #pragma unroll
        for (int nl = 0; nl < 4; ++nl) {
            const float bv = bg[(wv*4 + nl)*16 + ln15];
            #pragma unroll
            for (int rt = 0; rt < 2; ++rt) acc[rt][nl] = (f32x4){bv, bv, bv, bv};
        }
        bf16x8 bcur[4];
        #pragma unroll
        for (int nl = 0; nl < 4; ++nl) bcur[nl] = bp[nl*64];
        for (int kt = 0; kt < 8; ++kt) {
            bf16x8 bnext[4];
            if (kt < 7) {
                #pragma unroll
                for (int nl = 0; nl < 4; ++nl) bnext[nl] = bp[(kt+1)*1024 + nl*64];
            }
            bf16x8 afr[2];
            #pragma unroll
            for (int rt = 0; rt < 2; ++rt) {
                const int row = rt*16 + ln15;
                const int byte = (row*512 + kt*64 + lhi*16) ^ ((row & 7) << 4);
                afr[rt] = *reinterpret_cast<const bf16x8*>(A + byte);
            }
            #pragma unroll
            for (int rt = 0; rt < 2; ++rt)
                #pragma unroll
                for (int nl = 0; nl < 4; ++nl)
                    acc[rt][nl] = MFMA16(afr[rt], bcur[nl], acc[rt][nl]);
            #pragma unroll
            for (int nl = 0; nl < 4; ++nl) bcur[nl] = bnext[nl];
        }
        if (l == 0) {
            #pragma unroll
            for (int rt = 0; rt < 2; ++rt)
                #pragma unroll
                for (int nl = 0; nl < 4; ++nl)
                    #pragma unroll
                    for (int q = 0; q < 4; ++q) {
                        const int row = rt*16 + lhi*4 + q;
                        const int cn  = (wv*4 + nl)*16 + ln15;
                        const int byte = (row*512 + cn*2) ^ ((row & 7) << 4);
                        *reinterpret_cast<u16*>(hb + byte) = f2bf(gelu_f(acc[rt][nl][q]));
                    }
            __syncthreads();
        }
    }

    // v = gelu(acc) + x -> hb (bf16) after l=1 hb frag reads complete
    __syncthreads();
    #pragma unroll
    for (int rt = 0; rt < 2; ++rt)
        #pragma unroll
        for (int nl = 0; nl < 4; ++nl)
            #pragma unroll
            for (int q = 0; q < 4; ++q) {
                const int row = rt*16 + lhi*4 + q;
                const int cn  = (wv*4 + nl)*16 + ln15;
                const int byte = (row*512 + cn*2) ^ ((row & 7) << 4);
                const float x = bf2f(*reinterpret_cast<const u16*>(xg + byte));
                *reinterpret_cast<u16*>(hb + byte) = f2bf(gelu_f(acc[rt][nl][q]) + x);
            }
    __syncthreads();

    // LN stats: row = t>>3 (0..31), oct = t&7 (cols oct*32..+32); shfl 1/2/4
    {
        const int row = t >> 3, oct = t & 7;
        const int rswz = (row & 7) << 4;
        uint4 raw[4];
        #pragma unroll
        for (int i = 0; i < 4; ++i)
            raw[i] = *reinterpret_cast<const uint4*>(hb + ((row*512 + oct*64 + i*16) ^ rswz));
        float s = 0.f;
        #pragma unroll
        for (int i = 0; i < 4; ++i) {
            const unsigned u[4] = {raw[i].x, raw[i].y, raw[i].z, raw[i].w};
            #pragma unroll
            for (int w = 0; w < 4; ++w)
                s += bf2f((u16)(u[w] & 0xffffu)) + bf2f((u16)(u[w] >> 16));
        }
        s += __shfl_xor(s, 1); s += __shfl_xor(s, 2); s += __shfl_xor(s, 4);
        const float mu = s * (1.0f/256.0f);
        float ss = 0.f;
        #pragma unroll
        for (int i = 0; i < 4; ++i) {
            const unsigned u[4] = {raw[i].x, raw[i].y, raw[i].z, raw[i].w};
            #pragma unroll
            for (int w = 0; w < 4; ++w) {
                const float da = bf2f((u16)(u[w] & 0xffffu)) - mu;
                const float db = bf2f((u16)(u[w] >> 16)) - mu;
                ss += da*da + db*db;
            }
        }
        ss += __shfl_xor(ss, 1); ss += __shfl_xor(ss, 2); ss += __shfl_xor(ss, 4);
        const float sc = rsqrtf(ss * (1.0f/256.0f) + EPSV);
        if (oct == 0) { musc[row][0] = mu; musc[row][1] = sc; }
    }
    __syncthreads();

    // transposed writer: thread t = feature cn; read hb column, write 64B row
    {
        const int cn = t;
        const float ga  = gam[g*256 + cn];
        const float bt_ = bet[g*256 + cn];
        unsigned wds[16];
        #pragma unroll
        for (int rp = 0; rp < 16; ++rp) {
            float o[2];
            #pragma unroll
            for (int h = 0; h < 2; ++h) {
                const int r = rp*2 + h;
                const u16 vv = *reinterpret_cast<const u16*>(
                    hb + ((r*512 + cn*2) ^ ((r & 7) << 4)));
                o[h] = (bf2f(vv) - musc[r][0]) * musc[r][1] * ga + bt_;
            }
            wds[rp] = pk2(o[0], o[1]);
        }
        uint4* dst = reinterpret_cast<uint4*>(h1T + (size_t)(g*256 + cn)*BB + b0);
        #pragma unroll
        for (int q = 0; q < 4; ++q)
            dst[q] = make_uint4(wds[q*4], wds[q*4+1], wds[q*4+2], wds[q*4+3]);
    }
}

// ---------------------------------------------------------------------------
// Kernel 3: SSR block 2, BM=32 (unchanged arithmetic from R9). R9 post-mortem:
// VGPR 88, zero spill, but Occupancy 23% (1 block/CU) -> barrier-latency
// bound. launch_bounds (512,2): cap 128 (no spill risk) + request 2 resident
// blocks so one block's barriers hide under the other's compute.
// ---------------------------------------------------------------------------
__global__ __launch_bounds__(512, 2)
void ssr2_mfma(const u16* __restrict__ h1T,   // [4096][BB]
               const int* __restrict__ idx,   // [G,256]
               const u16* __restrict__ wpack,
               const float* __restrict__ bias,
               const float* __restrict__ gam,
               const float* __restrict__ bet,
               u16* __restrict__ pssr) {      // [4][BB][256] bf16
    __shared__ char sm[32768];
    char* xg = sm;            // bf16 [32][256] swizzled
    char* hb = sm + 16384;

    const int bx = blockIdx.x;
    const int slot = bx & 7;                  // XCD id (heuristic bx%8)
    const int gset = slot >> 1;               // 0..3, pinned per XCD pair
    const int tile = ((slot & 1) << 8) | (bx >> 3);   // 0..511
    const int b0 = tile * 32;
    const int t = threadIdx.x, lane = t & 63, wv = t >> 6;
    const int ln15 = lane & 15, lhi = lane >> 4;
    const int gd = t >> 1, grh = t & 1;       // gather: feature, batch-half
    const int grow = t >> 4, gc16 = t & 15;   // LN/ssr: row, col-16-block

    float accs[16];
    #pragma unroll
    for (int j = 0; j < 16; ++j) accs[j] = 0.f;

    uint4 nx[2];
    {   // prologue: load group gset*4
        const int col = idx[(gset*4)*256 + gd];
        const uint4* src = reinterpret_cast<const uint4*>(h1T + (size_t)col*BB + b0 + grh*16);
        nx[0] = src[0]; nx[1] = src[1];
    }

    for (int gi = 0; gi < 4; ++gi) {
        const int g = gset*4 + gi;
        __syncthreads();   // xg/hb free (prev LN done)
        // LDS-transpose write of gathered rows (uses nx -> implicit vmcnt wait)
        #pragma unroll
        for (int j = 0; j < 2; ++j) {
            const unsigned uu[4] = {nx[j].x, nx[j].y, nx[j].z, nx[j].w};
            #pragma unroll
            for (int k = 0; k < 8; ++k) {
                const int r = grh*16 + j*8 + k;
                const int byte = (r*512 + gd*2) ^ ((r & 7) << 4);
                *reinterpret_cast<u16*>(xg + byte) =
                    (k & 1) ? (u16)(uu[k >> 1] >> 16) : (u16)(uu[k >> 1] & 0xffffu);
            }
        }
        if (gi < 3) {   // T14: prefetch next group's rows under the MFMA phases
            const int col = idx[(g + 1)*256 + gd];
            const uint4* src = reinterpret_cast<const uint4*>(h1T + (size_t)col*BB + b0 + grh*16);
            nx[0] = src[0]; nx[1] = src[1];
        }
        __syncthreads();

        f32x4 acc[2][2];
        for (int l = 0; l < 2; ++l) {
            const char* A = l ? hb : xg;
            const bf16x8* bp = reinterpret_cast<const bf16x8*>(wpack)
                             + ((size_t)(32 + g*2 + l) * 128 + wv*2) * 64 + lane;
            const float* bg = bias + (g*2 + l) * 256;
            #pragma unroll
            for (int nl = 0; nl < 2; ++nl) {
                const float bv = bg[(wv*2 + nl)*16 + ln15];
                #pragma unroll
                for (int rt = 0; rt < 2; ++rt) acc[rt][nl] = (f32x4){bv, bv, bv, bv};
            }
            bf16x8 bcur[2];
            bcur[0] = bp[0]; bcur[1] = bp[64];
            for (int kt = 0; kt < 8; ++kt) {
                bf16x8 bnext[2];
                if (kt < 7) { bnext[0] = bp[(kt+1)*1024]; bnext[1] = bp[(kt+1)*1024 + 64]; }
                bf16x8 afr[2];
                #pragma unroll
                for (int rt = 0; rt < 2; ++rt) {
                    const int row = rt*16 + ln15;
                    const int byte = (row*512 + kt*64 + lhi*16) ^ ((row & 7) << 4);
                    afr[rt] = *reinterpret_cast<const bf16x8*>(A + byte);
                }
                #pragma unroll
                for (int rt = 0; rt < 2; ++rt) {
                    acc[rt][0] = MFMA16(afr[rt], bcur[0], acc[rt][0]);
                    acc[rt][1] = MFMA16(afr[rt], bcur[1], acc[rt][1]);
                }
                bcur[0] = bnext[0]; bcur[1] = bnext[1];
            }
            if (l == 0) {
                #pragma unroll
                for (int rt = 0; rt < 2; ++rt)
                    #pragma unroll
                    for (int nl = 0; nl < 2; ++nl)
                        #pragma unroll
                        for (int q = 0; q < 4; ++q) {
                            const int row = rt*16 + lhi*4 + q;
                            const int cn  = (wv*2 + nl)*16 + ln15;
                            const int byte = (row*512 + cn*2) ^ ((row & 7) << 4);
                            *reinterpret_cast<u16*>(hb + byte) = f2bf(gelu_f(acc[rt][nl][q]));
                        }
                __syncthreads();
            }
        }
        __syncthreads();   // l=1 hb frag reads done
        #pragma unroll
        for (int rt = 0; rt < 2; ++rt)
            #pragma unroll
            for (int nl = 0; nl < 2; ++nl)
                #pragma unroll
                for (int q = 0; q < 4; ++q) {
                    const int row = rt*16 + lhi*4 + q;
                    const int cn  = (wv*2 + nl)*16 + ln15;
                    const int byte = (row*512 + cn*2) ^ ((row & 7) << 4);
                    const float x = bf2f(*reinterpret_cast<const u16*>(xg + byte));
                    *reinterpret_cast<u16*>(hb + byte) = f2bf(gelu_f(acc[rt][nl][q]) + x);
                }
        __syncthreads();

        // LN + ssr accumulate: row = grow (0..31), cols gc16*16..+16.
        // 16 threads/row -> shfl_xor over 1,2,4,8 (lane groups of 16).
        {
            const int rswz = (grow & 7) << 4;
            uint4 raw[2];
            #pragma unroll
            for (int i = 0; i < 2; ++i)
                raw[i] = *reinterpret_cast<const uint4*>(hb + ((grow*512 + gc16*32 + i*16) ^ rswz));
            float s = 0.f;
            #pragma unroll
            for (int i = 0; i < 2; ++i) {
                const unsigned u[4] = {raw[i].x, raw[i].y, raw[i].z, raw[i].w};
                #pragma unroll
                for (int w = 0; w < 4; ++w)
                    s += bf2f((u16)(u[w] & 0xffffu)) + bf2f((u16)(u[w] >> 16));
            }
            s += __shfl_xor(s, 1); s += __shfl_xor(s, 2);
            s += __shfl_xor(s, 4); s += __shfl_xor(s, 8);
            const float mu = s * (1.0f/256.0f);
            float ss = 0.f;
            #pragma unroll
            for (int i = 0; i < 2; ++i) {
                const unsigned u[4] = {raw[i].x, raw[i].y, raw[i].z, raw[i].w};
                #pragma unroll
                for (int w = 0; w < 4; ++w) {
                    const float da = bf2f((u16)(u[w] & 0xffffu)) - mu;
                    const float db = bf2f((u16)(u[w] >> 16)) - mu;
                    ss += da*da + db*db;
                }
            }
            ss += __shfl_xor(ss, 1); ss += __shfl_xor(ss, 2);
            ss += __shfl_xor(ss, 4); ss += __shfl_xor(ss, 8);
            const float sc = rsqrtf(ss * (1.0f/256.0f) + EPSV);
            const float4* gap = reinterpret_cast<const float4*>(gam + g*256 + gc16*16);
            const float4* btp = reinterpret_cast<const float4*>(bet + g*256 + gc16*16);
            #pragma unroll
            for (int i = 0; i < 2; ++i) {
                const unsigned u[4] = {raw[i].x, raw[i].y, raw[i].z, raw[i].w};
                const float4 ga0 = gap[i*2],   bt0 = btp[i*2];
                const float4 ga1 = gap[i*2+1], bt1 = btp[i*2+1];
                const float gaa[8] = {ga0.x,ga0.y,ga0.z,ga0.w, ga1.x,ga1.y,ga1.z,ga1.w};
                const float bta[8] = {bt0.x,bt0.y,bt0.z,bt0.w, bt1.x,bt1.y,bt1.z,bt1.w};
                #pragma unroll
                for (int w = 0; w < 4; ++w) {
                    const float a = bf2f((u16)(u[w] & 0xffffu));
                    const float b = bf2f((u16)(u[w] >> 16));
                    accs[i*8 + w*2]     = fmaf((a - mu)*sc*gaa[w*2]   + bta[w*2],
                                               0.0625f, accs[i*8 + w*2]);
                    accs[i*8 + w*2 + 1] = fmaf((b - mu)*sc*gaa[w*2+1] + bta[w*2+1],
                                               0.0625f, accs[i*8 + w*2 + 1]);
                }
            }
        }
        // loop-top barrier orders these hb/xg reads vs next gather writes
    }

    // store bf16 partial ssr (contiguous 32B per thread, coalesced)
    u16* dst = pssr + ((size_t)gset*BB + b0 + grow)*256 + gc16*16;
    #pragma unroll
    for (int q = 0; q < 2; ++q)
        reinterpret_cast<uint4*>(dst)[q] =
            make_uint4(pk2(accs[q*8+0], accs[q*8+1]), pk2(accs[q*8+2], accs[q*8+3]),
                       pk2(accs[q*8+4], accs[q*8+5]), pk2(accs[q*8+6], accs[q*8+7]));
}

// ---------------------------------------------------------------------------
// Kernel 4: head. grid 256, 256 thr. ssr = sum of 4 bf16 partials;
// hid = relu(ssr@Wp1+bp1); out = sigmoid(hid@Wp2+bp2).
// ---------------------------------------------------------------------------
__global__ __launch_bounds__(256)
void head_kernel(const u16* __restrict__ pssr,   // [4][BB][256] bf16
                 const float* __restrict__ Wp1,  // [256,64]
                 const float* __restrict__ bp1,
                 const float* __restrict__ Wp2,
                 const float* __restrict__ bp2,
                 float* __restrict__ outp) {
    __shared__ float ssr_s[64 * 256];   // 64KB
    __shared__ float wp1_s[256 * 64];   // 64KB
    const int b0 = blockIdx.x * 64;
    const int t  = threadIdx.x;
    #pragma unroll
    for (int i = 0; i < 8; ++i) {
        const int u = t + i*256;               // uint4 id 0..2047 (8 bf16 each)
        const int row = u >> 5, c8 = u & 31;   // 32 uint4 per 256-col row
        float o[8] = {0,0,0,0,0,0,0,0};
        #pragma unroll
        for (int p = 0; p < 4; ++p) {
            const uint4 raw = reinterpret_cast<const uint4*>(
                pssr + (size_t)p*BB*256)[(size_t)(b0 + row)*32 + c8];
            const unsigned uu[4] = {raw.x, raw.y, raw.z, raw.w};
            #pragma unroll
            for (int w = 0; w < 4; ++w) {
                o[w*2]   += bf2f((u16)(uu[w] & 0xffffu));
                o[w*2+1] += bf2f((u16)(uu[w] >> 16));
            }
        }
        #pragma unroll
        for (int w = 0; w < 2; ++w)
            reinterpret_cast<float4*>(ssr_s + row*256 + c8*8)[w] =
                make_float4(o[w*4], o[w*4+1], o[w*4+2], o[w*4+3]);
    }
    #pragma unroll
    for (int i = 0; i < 16; ++i)
        reinterpret_cast<float4*>(wp1_s)[t + i*256] =
            reinterpret_cast<const float4*>(Wp1)[t + i*256];
    __syncthreads();
    const int j = t & 63, rq = t >> 6;
    const float w2j = Wp2[j], b1j = bp1[j], b2v = bp2[0];
    for (int k = 0; k < 16; ++k) {
        const int row = k*4 + rq;
        const float* sr = ssr_s + row*256;
        float s = b1j;
        #pragma unroll 8
        for (int d = 0; d < 256; ++d)
            s = fmaf(sr[d], wp1_s[d*64 + j], s);
        s = fmaxf(s, 0.f) * w2j;
        #pragma unroll
        for (int mm = 1; mm < 64; mm <<= 1) s += __shfl_xor(s, mm);
        if (j == 0) outp[b0 + row] = 1.0f / (1.0f + expf(-(s + b2v)));
    }
}

// ---------------------------------------------------------------------------
extern "C" void kernel_launch(void* const* d_in, const int* in_sizes, int n_in,
                              void* d_out, int out_size, void* d_ws, size_t ws_size,
                              hipStream_t stream) {
    const int*   fidx  = (const int*)  d_in[0];
    const float* fval  = (const float*)d_in[1];
    const float* table = (const float*)d_in[2];
    const float* ge    = (const float*)d_in[3];
    const float* be    = (const float*)d_in[4];
    const int*   idx1  = (const int*)  d_in[5];
    const float* W1    = (const float*)d_in[6];
    const float* b1    = (const float*)d_in[7];
    const float* g1    = (const float*)d_in[8];
    const float* be1   = (const float*)d_in[9];
    const int*   idx2  = (const int*)  d_in[10];
    const float* W2    = (const float*)d_in[11];
    const float* b2    = (const float*)d_in[12];
    const float* g2    = (const float*)d_in[13];
    const float* be2   = (const float*)d_in[14];
    const float* Wp1   = (const float*)d_in[15];
    const float* bp1   = (const float*)d_in[16];
    const float* Wp2   = (const float*)d_in[17];
    const float* bp2   = (const float*)d_in[18];
    float* out = (float*)d_out;

    // ws: wpack 8.4MB | xflatT bf16 [1024][BB] 32MB (overlaid by pssr bf16
    // [4][BB][256] 32MB after ssr1) | h1T bf16 [4096][BB] 128MB  (~168MB)
    const size_t wpack_elems = (size_t)64 * 8 * 16 * 64 * 8;
    const size_t need = wpack_elems*2 + (size_t)BB*1024*2 + (size_t)BB*GD*2;
    if (ws_size < need) {
        hipMemsetAsync(d_out, 0, (size_t)out_size * sizeof(float), stream);
        return;
    }
    u16* wpack = (u16*)d_ws;
    u16* xT    = wpack + wpack_elems;
    u16* pssr  = xT;                           // overlay (xT dead after ssr1)
    u16* h1T   = xT + (size_t)BB * 1024;

    prepack_kernel<<<2048, 256, 0, stream>>>(W1, W2, wpack);
    embed_ln_kernel<<<1024, 256, 0, stream>>>(fidx, fval, table, ge, be, xT);
    ssr1_mfma<<<8192, 256, 0, stream>>>(xT, idx1, wpack, b1, g1, be1, h1T);
    ssr2_mfma<<<2048, 512, 0, stream>>>(h1T, idx2, wpack, b2, g2, be2, pssr);
    head_kernel<<<256, 256, 0, stream>>>(pssr, Wp1, bp1, Wp2, bp2, out);
}